// Round 3
// baseline (1684.765 us; speedup 1.0000x reference)
//
#include <hip/hip_runtime.h>
#include <hip/hip_bf16.h>
#include <stdint.h>

#define B_ 32
#define T_ 128
#define H_ 1024
#define V_ 32000
#define NBLK_REC 64

typedef unsigned short u16;
typedef __attribute__((ext_vector_type(8))) short short8;
typedef __attribute__((ext_vector_type(4))) float f32x4;

static __device__ __forceinline__ u16 f2bf(float f) {
    uint32_t u = __float_as_uint(f);
    uint32_t r = (u + 0x7FFFu + ((u >> 16) & 1u)) >> 16;
    return (u16)r;
}

static __device__ __forceinline__ float sigmf(float x) {
    return 1.0f / (1.0f + __expf(-x));
}

static __device__ __forceinline__ float tanh_f(float x) {
    x = fminf(fmaxf(x, -20.f), 20.f);
    float e = __expf(2.f * x);
    return (e - 1.f) / (e + 1.f);
}

// Direct global->LDS 16B copy (CK-style addrspace casts; dest is wave-uniform
// base + lane*16 in HW, so LDS layout must be linear in lane order).
static __device__ __forceinline__ void gload16(const void* g, void* l) {
    __builtin_amdgcn_global_load_lds(
        (const __attribute__((address_space(1))) uint32_t*)g,
        (__attribute__((address_space(3))) uint32_t*)(uint32_t)(uintptr_t)l,
        16, 0, 0);
}

// ---------------------------------------------------------------------------
// Prep: W_comb = W_ih[:,1:] + W_hh  (bf16), wx = W_ih[:,0], biasc = b_ih+b_hh
// Also zeroes the 64 producer flags (must be re-zeroed every launch/replay).
// ---------------------------------------------------------------------------
__global__ void prep_w(const float* __restrict__ Wih, const float* __restrict__ Whh,
                       const float* __restrict__ bih, const float* __restrict__ bhh,
                       u16* __restrict__ Wc, float* __restrict__ wx, float* __restrict__ biasc,
                       unsigned* __restrict__ flags) {
    int idx = blockIdx.x * 256 + threadIdx.x;      // 4096*1024 threads
    int r = idx >> 10, k = idx & 1023;
    float v = Wih[r * (H_ + 1) + 1 + k] + Whh[idx];
    Wc[idx] = f2bf(v);
    if (k == 0) {
        wx[r] = Wih[r * (H_ + 1)];
        biasc[r] = bih[r] + bhh[r];
    }
    if (idx < NBLK_REC) flags[idx] = 0u;
}

// W_out fp32 -> bf16
__global__ void prep_wout(const float* __restrict__ Wout, u16* __restrict__ Wo) {
    long long i = (long long)(blockIdx.x) * 256 + threadIdx.x;   // x4 elements each
    f32x4 v = *(const f32x4*)(Wout + i * 4);
    uint2 o;
    o.x = (uint32_t)f2bf(v[0]) | ((uint32_t)f2bf(v[1]) << 16);
    o.y = (uint32_t)f2bf(v[2]) | ((uint32_t)f2bf(v[3]) << 16);
    *(uint2*)(Wo + i * 4) = o;
}

// ---------------------------------------------------------------------------
// Init: h0 = enc @ W_h^T (bf16), c0 = enc @ W_c^T (fp32).
// One wave per (sel, j) row; W-row held in registers, reused for all 32 b.
// ---------------------------------------------------------------------------
__global__ void init_hc(const float* __restrict__ enc, const float* __restrict__ Wh,
                        const float* __restrict__ Wcp, u16* __restrict__ h0,
                        float* __restrict__ c0) {
    int gwid = blockIdx.x * 4 + (threadIdx.x >> 6);   // 2048 waves
    int lane = threadIdx.x & 63;
    int sel = gwid >> 10;                // 0: h, 1: c
    int j = gwid & 1023;
    const float* W = sel ? Wcp : Wh;
    const float* wrow = W + (size_t)j * H_;
    f32x4 wv[4];
#pragma unroll
    for (int it = 0; it < 4; ++it)
        wv[it] = *(const f32x4*)(wrow + it * 256 + lane * 4);
#pragma unroll 2
    for (int b = 0; b < B_; ++b) {
        const float* erow = enc + (size_t)b * H_;
        float acc = 0.f;
#pragma unroll
        for (int it = 0; it < 4; ++it) {
            f32x4 ev = *(const f32x4*)(erow + it * 256 + lane * 4);
            acc += wv[it][0] * ev[0] + wv[it][1] * ev[1] + wv[it][2] * ev[2] + wv[it][3] * ev[3];
        }
#pragma unroll
        for (int s = 32; s >= 1; s >>= 1) acc += __shfl_xor(acc, s, 64);
        if (lane == 0) {
            if (sel) c0[(size_t)b * H_ + j] = acc;
            else     h0[(size_t)b * H_ + j] = f2bf(acc);
        }
    }
}

// ---------------------------------------------------------------------------
// Persistent LSTM recurrence. 64 blocks x 256 threads; block owns j0=bid*16.
// Weights in registers for all 128 steps. Sync via per-producer monotone
// flags: producer stores h_t (agent scope), __syncthreads (drains vmcnt of
// every thread), tid0 release-stores flags[bid]=t+1. Consumers poll all 64
// flags (lane l -> flags[l]), acquire-fence, then plain-load h.
// Blocks may drift (no global lockstep) — flags are monotone, h slots per t
// are disjoint, so no WAR hazards.
// ---------------------------------------------------------------------------
__global__ __launch_bounds__(256, 1) void lstm_persist(
    const u16* __restrict__ Wc, const float* __restrict__ wx,
    const float* __restrict__ biasc, const u16* __restrict__ h0,
    const float* __restrict__ c0, const float* __restrict__ y,
    u16* __restrict__ A, unsigned* __restrict__ flags) {
    __shared__ float red[4][64 * 33];    // per-wave partial sums, padded (33)
    __shared__ float cs[16][32];         // cell state [jl][b]
    __shared__ float wxs[64], bcs[64];   // per-row x-weight / bias

    int tid = threadIdx.x;
    int lane = tid & 63;
    int kw = tid >> 6;                   // wave id = K-slice
    int bid = blockIdx.x;
    int j0 = bid * 16;
    int jl = lane & 15;                  // A-row / B-col lane index
    int kc = (lane >> 4) * 8;            // k-offset within 32-chunk
    int q = tid >> 5, b = tid & 31;      // pointwise mapping

    // ---- one-time: weights to registers ----
    short8 afr[4][8];
    {
        const u16* abase = Wc + (size_t)(j0 + jl) * H_ + kw * 256 + kc;
#pragma unroll
        for (int g = 0; g < 4; ++g)
#pragma unroll
            for (int ks = 0; ks < 8; ++ks)
                afr[g][ks] = *(const short8*)(abase + (size_t)g * H_ * H_ + ks * 32);
    }
    // ---- one-time: stage wx/bias/c0 into LDS ----
    if (tid < 64) {
        int g = tid >> 4, jj = tid & 15;
        wxs[tid] = wx[(size_t)g * H_ + j0 + jj];
        bcs[tid] = biasc[(size_t)g * H_ + j0 + jj];
    }
    cs[2 * q][b]     = c0[(size_t)b * H_ + j0 + 2 * q];
    cs[2 * q + 1][b] = c0[(size_t)b * H_ + j0 + 2 * q + 1];
    __syncthreads();

    for (int t = 0; t < T_; ++t) {
        const u16* hp;
        size_t bst;
        if (t == 0) { hp = h0; bst = (size_t)H_; }
        else        { hp = A + (size_t)(t - 1) * H_; bst = (size_t)T_ * H_; }

        // ---- wait for all producers of h_{t-1} ----
        if (t > 0) {
            unsigned target = (unsigned)t;
            const unsigned* fp = &flags[lane];
            int guard = 0;
            for (;;) {
                unsigned v = __hip_atomic_load(fp, __ATOMIC_RELAXED, __HIP_MEMORY_SCOPE_AGENT);
                if (__all(v >= target)) break;
                if (++guard > 2000000) break;   // safety; never triggers co-resident
            }
            __builtin_amdgcn_fence(__ATOMIC_ACQUIRE, "agent");
        }

        float yv = y[b * T_ + t];

        // ---- load B-frags (h_prev) and MFMA ----
        short8 bfr0[8], bfr1[8];
        {
            const u16* hb = hp + (size_t)jl * bst + kw * 256 + kc;
#pragma unroll
            for (int ks = 0; ks < 8; ++ks) {
                bfr0[ks] = *(const short8*)(hb + ks * 32);
                bfr1[ks] = *(const short8*)(hb + (size_t)16 * bst + ks * 32);
            }
        }
        f32x4 acc[4][2] = {};
#pragma unroll
        for (int ks = 0; ks < 8; ++ks) {
#pragma unroll
            for (int g = 0; g < 4; ++g) {
                acc[g][0] = __builtin_amdgcn_mfma_f32_16x16x32_bf16(afr[g][ks], bfr0[ks], acc[g][0], 0, 0, 0);
                acc[g][1] = __builtin_amdgcn_mfma_f32_16x16x32_bf16(afr[g][ks], bfr1[ks], acc[g][1], 0, 0, 0);
            }
        }
        // ---- partials to LDS ----
        int r0 = (lane >> 4) * 4;
#pragma unroll
        for (int g = 0; g < 4; ++g)
#pragma unroll
            for (int bt = 0; bt < 2; ++bt)
#pragma unroll
                for (int r = 0; r < 4; ++r)
                    red[kw][(g * 16 + r0 + r) * 33 + bt * 16 + jl] = acc[g][bt][r];
        __syncthreads();

        // ---- pointwise cell update; write h_t (agent-scope, L1-bypass) ----
        {
            float hv[2];
#pragma unroll
            for (int s = 0; s < 2; ++s) {
                int jlx = 2 * q + s;
                float pre[4];
#pragma unroll
                for (int g = 0; g < 4; ++g) {
                    int row = (g * 16 + jlx) * 33 + b;
                    pre[g] = red[0][row] + red[1][row] + red[2][row] + red[3][row]
                           + wxs[g * 16 + jlx] * yv + bcs[g * 16 + jlx];
                }
                float iv = sigmf(pre[0]);
                float fv = sigmf(pre[1]);
                float gv = tanh_f(pre[2]);
                float ov = sigmf(pre[3]);
                float cv = fv * cs[jlx][b] + iv * gv;
                cs[jlx][b] = cv;
                hv[s] = ov * tanh_f(cv);
            }
            uint32_t pk = (uint32_t)f2bf(hv[0]) | ((uint32_t)f2bf(hv[1]) << 16);
            __hip_atomic_store((uint32_t*)(A + ((size_t)b * T_ + t) * H_ + j0 + 2 * q),
                               pk, __ATOMIC_RELAXED, __HIP_MEMORY_SCOPE_AGENT);
        }
        // Drains every thread's vmcnt before the barrier completes -> all h_t
        // stores are globally visible; also protects red[] for next iter.
        __syncthreads();
        if (tid == 0)
            __hip_atomic_store(&flags[bid], (unsigned)(t + 1),
                               __ATOMIC_RELEASE, __HIP_MEMORY_SCOPE_AGENT);
    }
}

// ---------------------------------------------------------------------------
// Output GEMM: C[m][n] = sum_k A[m][k] * Wo[n][k] + b_out[n]
// m97 structure: 128x128 tile, BK=32, global_load_lds width-16 staging into
// linear LDS (lane order == tid*16B), 2 barriers per K-step, XCD-bijective
// block swizzle (32 consecutive blocks share a W_out panel -> same XCD L2).
// ---------------------------------------------------------------------------
__global__ __launch_bounds__(256) void gemm_out(
    const u16* __restrict__ A, const u16* __restrict__ Wo,
    const float* __restrict__ bout, float* __restrict__ out) {
    __shared__ u16 As[128 * 32];
    __shared__ u16 Bs[128 * 32];

    int orig = blockIdx.x;                       // 8000 = 8 XCDs * 1000
    int w = (orig & 7) * 1000 + (orig >> 3);     // bijective XCD chunking
    int mb = w & 31;                             // 32 m-blocks (== batch b)
    int nb = w >> 5;                             // 250 n-blocks
    int m0 = mb * 128, n0 = nb * 128;

    int tid = threadIdx.x, lane = tid & 63, wid = tid >> 6;
    int wm = wid >> 1, wn = wid & 1;

    f32x4 acc[4][4] = {};

    int srow = tid >> 2;            // 0..63
    int scol = (tid & 3) * 8;       // k-offset within 32-chunk
    const u16* Ag = A + (size_t)(m0 + srow) * H_ + scol;
    const u16* Bg = Wo + (size_t)(n0 + srow) * H_ + scol;
    u16* AsD0 = &As[tid * 8];            // linear: byte off = tid*16
    u16* AsD1 = &As[64 * 32 + tid * 8];
    u16* BsD0 = &Bs[tid * 8];
    u16* BsD1 = &Bs[64 * 32 + tid * 8];

    int kc = (lane >> 4) * 8;
    int frow = lane & 15;

    for (int ks = 0; ks < 32; ++ks) {
        int k0 = ks * 32;
        __syncthreads();   // previous iter's frag reads done before overwrite
        gload16(Ag + k0, AsD0);
        gload16(Ag + (size_t)64 * H_ + k0, AsD1);
        gload16(Bg + k0, BsD0);
        gload16(Bg + (size_t)64 * H_ + k0, BsD1);
        __syncthreads();   // vmcnt(0) drain: staged tile visible

        short8 af[4], bf[4];
#pragma unroll
        for (int mt = 0; mt < 4; ++mt)
            af[mt] = *(const short8*)(&As[(wm * 64 + mt * 16 + frow) * 32 + kc]);
#pragma unroll
        for (int nt = 0; nt < 4; ++nt)
            bf[nt] = *(const short8*)(&Bs[(wn * 64 + nt * 16 + frow) * 32 + kc]);
#pragma unroll
        for (int mt = 0; mt < 4; ++mt)
#pragma unroll
            for (int nt = 0; nt < 4; ++nt)
                acc[mt][nt] = __builtin_amdgcn_mfma_f32_16x16x32_bf16(af[mt], bf[nt], acc[mt][nt], 0, 0, 0);
    }

    // Epilogue: C row = t index within batch mb, col = vocab n.
    int b = mb;
#pragma unroll
    for (int nt = 0; nt < 4; ++nt) {
        int n = n0 + wn * 64 + nt * 16 + (lane & 15);
        float bias = bout[n];
#pragma unroll
        for (int mt = 0; mt < 4; ++mt) {
            int trow = wm * 64 + mt * 16 + (lane >> 4) * 4;
            f32x4 v = acc[mt][nt];
            v[0] += bias; v[1] += bias; v[2] += bias; v[3] += bias;
            float* dst = out + ((size_t)b * V_ + n) * T_ + trow;
            *(f32x4*)dst = v;
        }
    }
}

// ---------------------------------------------------------------------------
extern "C" void kernel_launch(void* const* d_in, const int* in_sizes, int n_in,
                              void* d_out, int out_size, void* d_ws, size_t ws_size,
                              hipStream_t stream) {
    const float* y    = (const float*)d_in[0];   // [B,T]
    const float* enc  = (const float*)d_in[1];   // [B,H]
    const float* Wh   = (const float*)d_in[2];   // [H,H]
    const float* Wcp  = (const float*)d_in[3];   // [H,H]
    const float* Wih  = (const float*)d_in[4];   // [4H,1+H]
    const float* Whh  = (const float*)d_in[5];   // [4H,H]
    const float* bih  = (const float*)d_in[6];   // [4H]
    const float* bhh  = (const float*)d_in[7];   // [4H]
    const float* Wout = (const float*)d_in[8];   // [V,H]
    const float* bout = (const float*)d_in[9];   // [V]

    uint8_t* ws = (uint8_t*)d_ws;
    u16*  Wcomb = (u16*)ws;                                   // 4096*1024*2  = 8,388,608
    u16*  Wo    = (u16*)(ws + 8388608);                       // 32000*1024*2 = 65,536,000
    float* wx    = (float*)(ws + 8388608 + 65536000);         // 4096*4
    float* biasc = wx + 4096;                                 // 4096*4
    u16*  h0    = (u16*)(biasc + 4096);                       // 32*1024*2
    float* c     = (float*)(h0 + 32 * 1024);                  // 32*1024*4
    u16*  A     = (u16*)(c + 32 * 1024);                      // 4096*1024*2
    unsigned* flags = (unsigned*)(A + (size_t)4096 * 1024);   // 64*4 B

    prep_w<<<16384, 256, 0, stream>>>(Wih, Whh, bih, bhh, Wcomb, wx, biasc, flags);
    prep_wout<<<32000, 256, 0, stream>>>(Wout, Wo);
    init_hc<<<512, 256, 0, stream>>>(enc, Wh, Wcp, h0, c);

    lstm_persist<<<NBLK_REC, 256, 0, stream>>>(Wcomb, wx, biasc, h0, c, y, A, flags);

    gemm_out<<<8000, 256, 0, stream>>>(A, Wo, bout, (float*)d_out);
}

// Round 4
// 1350.319 us; speedup vs baseline: 1.2477x; 1.2477x over previous
//
#include <hip/hip_runtime.h>
#include <hip/hip_bf16.h>
#include <stdint.h>

#define B_ 32
#define T_ 128
#define H_ 1024
#define V_ 32000
#define NBLK_REC 64

typedef unsigned short u16;
typedef __attribute__((ext_vector_type(8))) short short8;
typedef __attribute__((ext_vector_type(4))) float f32x4;

static __device__ __forceinline__ u16 f2bf(float f) {
    uint32_t u = __float_as_uint(f);
    uint32_t r = (u + 0x7FFFu + ((u >> 16) & 1u)) >> 16;
    return (u16)r;
}

static __device__ __forceinline__ float sigmf(float x) {
    return 1.0f / (1.0f + __expf(-x));
}

static __device__ __forceinline__ float tanh_f(float x) {
    x = fminf(fmaxf(x, -20.f), 20.f);
    float e = __expf(2.f * x);
    return (e - 1.f) / (e + 1.f);
}

// Direct global->LDS 16B copy (dest is wave-uniform base + lane*16 in HW).
static __device__ __forceinline__ void gload16(const void* g, void* l) {
    __builtin_amdgcn_global_load_lds(
        (const __attribute__((address_space(1))) uint32_t*)g,
        (__attribute__((address_space(3))) uint32_t*)(uint32_t)(uintptr_t)l,
        16, 0, 0);
}

// ---------------------------------------------------------------------------
// Prep: W_comb = W_ih[:,1:] + W_hh  (bf16), wx = W_ih[:,0], biasc = b_ih+b_hh
// Also zeroes the 64 producer flags (re-zeroed every launch/replay).
// ---------------------------------------------------------------------------
__global__ void prep_w(const float* __restrict__ Wih, const float* __restrict__ Whh,
                       const float* __restrict__ bih, const float* __restrict__ bhh,
                       u16* __restrict__ Wc, float* __restrict__ wx, float* __restrict__ biasc,
                       unsigned* __restrict__ flags) {
    int idx = blockIdx.x * 256 + threadIdx.x;      // 4096*1024 threads
    int r = idx >> 10, k = idx & 1023;
    float v = Wih[r * (H_ + 1) + 1 + k] + Whh[idx];
    Wc[idx] = f2bf(v);
    if (k == 0) {
        wx[r] = Wih[r * (H_ + 1)];
        biasc[r] = bih[r] + bhh[r];
    }
    if (idx < NBLK_REC) flags[idx] = 0u;
}

// W_out fp32 -> bf16
__global__ void prep_wout(const float* __restrict__ Wout, u16* __restrict__ Wo) {
    long long i = (long long)(blockIdx.x) * 256 + threadIdx.x;   // x4 elements each
    f32x4 v = *(const f32x4*)(Wout + i * 4);
    uint2 o;
    o.x = (uint32_t)f2bf(v[0]) | ((uint32_t)f2bf(v[1]) << 16);
    o.y = (uint32_t)f2bf(v[2]) | ((uint32_t)f2bf(v[3]) << 16);
    *(uint2*)(Wo + i * 4) = o;
}

// ---------------------------------------------------------------------------
// Init: h0 = enc @ W_h^T (bf16), c0 = enc @ W_c^T (fp32).
// One wave per (sel, j) row; W-row held in registers, reused for all 32 b.
// ---------------------------------------------------------------------------
__global__ void init_hc(const float* __restrict__ enc, const float* __restrict__ Wh,
                        const float* __restrict__ Wcp, u16* __restrict__ h0,
                        float* __restrict__ c0) {
    int gwid = blockIdx.x * 4 + (threadIdx.x >> 6);   // 2048 waves
    int lane = threadIdx.x & 63;
    int sel = gwid >> 10;                // 0: h, 1: c
    int j = gwid & 1023;
    const float* W = sel ? Wcp : Wh;
    const float* wrow = W + (size_t)j * H_;
    f32x4 wv[4];
#pragma unroll
    for (int it = 0; it < 4; ++it)
        wv[it] = *(const f32x4*)(wrow + it * 256 + lane * 4);
#pragma unroll 2
    for (int b = 0; b < B_; ++b) {
        const float* erow = enc + (size_t)b * H_;
        float acc = 0.f;
#pragma unroll
        for (int it = 0; it < 4; ++it) {
            f32x4 ev = *(const f32x4*)(erow + it * 256 + lane * 4);
            acc += wv[it][0] * ev[0] + wv[it][1] * ev[1] + wv[it][2] * ev[2] + wv[it][3] * ev[3];
        }
#pragma unroll
        for (int s = 32; s >= 1; s >>= 1) acc += __shfl_xor(acc, s, 64);
        if (lane == 0) {
            if (sel) c0[(size_t)b * H_ + j] = acc;
            else     h0[(size_t)b * H_ + j] = f2bf(acc);
        }
    }
}

// ---------------------------------------------------------------------------
// Persistent LSTM recurrence. 64 blocks x 256 threads; block owns j0=bid*16.
// Weights in registers for all 128 steps. Sync: producer stores h_t
// (agent-scope write-through), __syncthreads (drains every thread's vmcnt),
// tid0 relaxed-stores flags[bid]=t+1. Consumer: WAVE 0 ONLY polls flags[lane]
// with s_sleep backoff (one coalesced 256B load/iter), compiler acquire fence
// only (NO hw cache invalidate — h lines are first-touch at the reader;
// validated r2), then __syncthreads releases the block.
// ---------------------------------------------------------------------------
__global__ __launch_bounds__(256, 1) void lstm_persist(
    const u16* __restrict__ Wc, const float* __restrict__ wx,
    const float* __restrict__ biasc, const u16* __restrict__ h0,
    const float* __restrict__ c0, const float* __restrict__ y,
    u16* __restrict__ A, unsigned* __restrict__ flags) {
    __shared__ float red[4][64 * 33];    // per-wave partial sums, padded (33)
    __shared__ float cs[16][32];         // cell state [jl][b]
    __shared__ float wxs[64], bcs[64];   // per-row x-weight / bias
    __shared__ float ys[32 * 129];       // y staged, padded stride 129

    int tid = threadIdx.x;
    int lane = tid & 63;
    int kw = tid >> 6;                   // wave id = K-slice
    int bid = blockIdx.x;
    int j0 = bid * 16;
    int jl = lane & 15;                  // A-row / B-col lane index
    int kc = (lane >> 4) * 8;            // k-offset within 32-chunk
    int q = tid >> 5, b = tid & 31;      // pointwise mapping

    // ---- one-time: weights to registers ----
    short8 afr[4][8];
    {
        const u16* abase = Wc + (size_t)(j0 + jl) * H_ + kw * 256 + kc;
#pragma unroll
        for (int g = 0; g < 4; ++g)
#pragma unroll
            for (int ks = 0; ks < 8; ++ks)
                afr[g][ks] = *(const short8*)(abase + (size_t)g * H_ * H_ + ks * 32);
    }
    // ---- one-time: stage wx/bias/c0/y into LDS ----
    if (tid < 64) {
        int g = tid >> 4, jj = tid & 15;
        wxs[tid] = wx[(size_t)g * H_ + j0 + jj];
        bcs[tid] = biasc[(size_t)g * H_ + j0 + jj];
    }
#pragma unroll
    for (int i = tid; i < B_ * T_; i += 256)
        ys[(i >> 7) * 129 + (i & 127)] = y[i];
    cs[2 * q][b]     = c0[(size_t)b * H_ + j0 + 2 * q];
    cs[2 * q + 1][b] = c0[(size_t)b * H_ + j0 + 2 * q + 1];
    __syncthreads();

    for (int t = 0; t < T_; ++t) {
        const u16* hp;
        size_t bst;
        if (t == 0) { hp = h0; bst = (size_t)H_; }
        else        { hp = A + (size_t)(t - 1) * H_; bst = (size_t)T_ * H_; }

        // ---- wait for all producers of h_{t-1}: wave 0 polls, rest park ----
        if (t > 0) {
            if (kw == 0) {
                unsigned target = (unsigned)t;
                const unsigned* fp = &flags[lane];
                int guard = 0;
                for (;;) {
                    unsigned v = __hip_atomic_load(fp, __ATOMIC_RELAXED, __HIP_MEMORY_SCOPE_AGENT);
                    if (__all(v >= target)) break;
                    __builtin_amdgcn_s_sleep(1);
                    if (++guard > 10000000) break;   // safety; never triggers co-resident
                }
                __atomic_signal_fence(__ATOMIC_ACQUIRE);
            }
            __syncthreads();
        }

        // ---- load B-frags (h_prev) and MFMA ----
        short8 bfr0[8], bfr1[8];
        {
            const u16* hb = hp + (size_t)jl * bst + kw * 256 + kc;
#pragma unroll
            for (int ks = 0; ks < 8; ++ks) {
                bfr0[ks] = *(const short8*)(hb + ks * 32);
                bfr1[ks] = *(const short8*)(hb + (size_t)16 * bst + ks * 32);
            }
        }
        f32x4 acc[4][2] = {};
#pragma unroll
        for (int ks = 0; ks < 8; ++ks) {
#pragma unroll
            for (int g = 0; g < 4; ++g) {
                acc[g][0] = __builtin_amdgcn_mfma_f32_16x16x32_bf16(afr[g][ks], bfr0[ks], acc[g][0], 0, 0, 0);
                acc[g][1] = __builtin_amdgcn_mfma_f32_16x16x32_bf16(afr[g][ks], bfr1[ks], acc[g][1], 0, 0, 0);
            }
        }
        // ---- partials to LDS ----
        int r0 = (lane >> 4) * 4;
#pragma unroll
        for (int g = 0; g < 4; ++g)
#pragma unroll
            for (int bt = 0; bt < 2; ++bt)
#pragma unroll
                for (int r = 0; r < 4; ++r)
                    red[kw][(g * 16 + r0 + r) * 33 + bt * 16 + jl] = acc[g][bt][r];
        __syncthreads();

        // ---- pointwise cell update; write h_t (agent-scope, L1-bypass) ----
        {
            float yv = ys[b * 129 + t];
            float hv[2];
#pragma unroll
            for (int s = 0; s < 2; ++s) {
                int jlx = 2 * q + s;
                float pre[4];
#pragma unroll
                for (int g = 0; g < 4; ++g) {
                    int row = (g * 16 + jlx) * 33 + b;
                    pre[g] = red[0][row] + red[1][row] + red[2][row] + red[3][row]
                           + wxs[g * 16 + jlx] * yv + bcs[g * 16 + jlx];
                }
                float iv = sigmf(pre[0]);
                float fv = sigmf(pre[1]);
                float gv = tanh_f(pre[2]);
                float ov = sigmf(pre[3]);
                float cv = fv * cs[jlx][b] + iv * gv;
                cs[jlx][b] = cv;
                hv[s] = ov * tanh_f(cv);
            }
            uint32_t pk = (uint32_t)f2bf(hv[0]) | ((uint32_t)f2bf(hv[1]) << 16);
            __hip_atomic_store((uint32_t*)(A + ((size_t)b * T_ + t) * H_ + j0 + 2 * q),
                               pk, __ATOMIC_RELAXED, __HIP_MEMORY_SCOPE_AGENT);
        }
        // Drains every thread's vmcnt -> all h_t stores at the coherence
        // point; also protects red[]/cs[] for next iter.
        __syncthreads();
        if (tid == 0)
            __hip_atomic_store(&flags[bid], (unsigned)(t + 1),
                               __ATOMIC_RELAXED, __HIP_MEMORY_SCOPE_AGENT);
    }
}

// ---------------------------------------------------------------------------
// Output GEMM: C[m][n] = sum_k A[m][k] * Wo[n][k] + b_out[n]
// m = b*T + t; with T=128 each 128-row m-tile is exactly batch b, t in [0,128).
// 128x128 tile, BK=32, global_load_lds width-16 linear staging, XCD-bijective
// swizzle. Epilogue transposes C through LDS so global stores are contiguous
// 512B rows along t (kills the 16B/512B-stride RFO pattern of r1-r3).
// ---------------------------------------------------------------------------
#define TRS 132   // transpose-buffer row stride in words (528B): <=2-way banks
__global__ __launch_bounds__(256) void gemm_out(
    const u16* __restrict__ A, const u16* __restrict__ Wo,
    const float* __restrict__ bout, float* __restrict__ out) {
    __shared__ __align__(16) uint8_t smem[32 * TRS * 4];   // 16896B; aliases staging
    u16* As = (u16*)smem;               // 128*32 u16 = 8KB
    u16* Bs = As + 128 * 32;            // 8KB
    float* tr = (float*)smem;           // epilogue transpose buffer

    int orig = blockIdx.x;                       // 8000 = 8 XCDs * 1000
    int w = (orig & 7) * 1000 + (orig >> 3);     // bijective XCD chunking
    int mb = w & 31;                             // m-block == batch b
    int nb = w >> 5;                             // 250 n-blocks
    int m0 = mb * 128, n0 = nb * 128;

    int tid = threadIdx.x, lane = tid & 63, wid = tid >> 6;
    int wm = wid >> 1, wn = wid & 1;

    f32x4 acc[4][4] = {};

    int srow = tid >> 2;            // 0..63
    int scol = (tid & 3) * 8;       // k-offset within 32-chunk
    const u16* Ag = A + (size_t)(m0 + srow) * H_ + scol;
    const u16* Bg = Wo + (size_t)(n0 + srow) * H_ + scol;
    u16* AsD0 = &As[tid * 8];            // linear: byte off = tid*16
    u16* AsD1 = &As[64 * 32 + tid * 8];
    u16* BsD0 = &Bs[tid * 8];
    u16* BsD1 = &Bs[64 * 32 + tid * 8];

    int kc = (lane >> 4) * 8;
    int frow = lane & 15;

    for (int ks = 0; ks < 32; ++ks) {
        int k0 = ks * 32;
        __syncthreads();   // previous iter's frag reads done before overwrite
        gload16(Ag + k0, AsD0);
        gload16(Ag + (size_t)64 * H_ + k0, AsD1);
        gload16(Bg + k0, BsD0);
        gload16(Bg + (size_t)64 * H_ + k0, BsD1);
        __syncthreads();   // vmcnt(0) drain: staged tile visible

        short8 af[4], bf[4];
#pragma unroll
        for (int mt = 0; mt < 4; ++mt)
            af[mt] = *(const short8*)(&As[(wm * 64 + mt * 16 + frow) * 32 + kc]);
#pragma unroll
        for (int nt = 0; nt < 4; ++nt)
            bf[nt] = *(const short8*)(&Bs[(wn * 64 + nt * 16 + frow) * 32 + kc]);
#pragma unroll
        for (int mt = 0; mt < 4; ++mt)
#pragma unroll
            for (int nt = 0; nt < 4; ++nt)
                acc[mt][nt] = __builtin_amdgcn_mfma_f32_16x16x32_bf16(af[mt], bf[nt], acc[mt][nt], 0, 0, 0);
    }

    // ---- epilogue: bias + transpose through LDS, coalesced t-major stores --
    float biasv[4];
#pragma unroll
    for (int nt = 0; nt < 4; ++nt)
        biasv[nt] = bout[n0 + wn * 64 + nt * 16 + (lane & 15)];

    int b = mb;
#pragma unroll
    for (int p = 0; p < 4; ++p) {
        __syncthreads();   // K-loop frag reads / previous pass reads done
        if (wn == (p >> 1)) {
#pragma unroll
            for (int hh = 0; hh < 2; ++hh) {
                int nt = (p & 1) * 2 + hh;
                int nl = ((nt & 1) << 4) + (lane & 15);   // row within 32-group
#pragma unroll
                for (int mt = 0; mt < 4; ++mt) {
                    f32x4 v = acc[mt][nt];
                    float bs = biasv[nt];
                    v[0] += bs; v[1] += bs; v[2] += bs; v[3] += bs;
                    int t = wm * 64 + mt * 16 + ((lane >> 4) << 2);
                    *(f32x4*)&tr[nl * TRS + t] = v;
                }
            }
        }
        __syncthreads();
        {
            int row = tid >> 3;              // 0..31
            int c0 = (tid & 7) * 16;         // float offset within t-row
            int n = n0 + p * 32 + row;
            float* dst = out + ((size_t)b * V_ + n) * T_ + c0;
            const float* srcp = &tr[row * TRS + c0];
            f32x4 v0 = *(const f32x4*)(srcp);
            f32x4 v1 = *(const f32x4*)(srcp + 4);
            f32x4 v2 = *(const f32x4*)(srcp + 8);
            f32x4 v3 = *(const f32x4*)(srcp + 12);
            *(f32x4*)(dst)      = v0;
            *(f32x4*)(dst + 4)  = v1;
            *(f32x4*)(dst + 8)  = v2;
            *(f32x4*)(dst + 12) = v3;
        }
    }
}

// ---------------------------------------------------------------------------
extern "C" void kernel_launch(void* const* d_in, const int* in_sizes, int n_in,
                              void* d_out, int out_size, void* d_ws, size_t ws_size,
                              hipStream_t stream) {
    const float* y    = (const float*)d_in[0];   // [B,T]
    const float* enc  = (const float*)d_in[1];   // [B,H]
    const float* Wh   = (const float*)d_in[2];   // [H,H]
    const float* Wcp  = (const float*)d_in[3];   // [H,H]
    const float* Wih  = (const float*)d_in[4];   // [4H,1+H]
    const float* Whh  = (const float*)d_in[5];   // [4H,H]
    const float* bih  = (const float*)d_in[6];   // [4H]
    const float* bhh  = (const float*)d_in[7];   // [4H]
    const float* Wout = (const float*)d_in[8];   // [V,H]
    const float* bout = (const float*)d_in[9];   // [V]

    uint8_t* ws = (uint8_t*)d_ws;
    u16*  Wcomb = (u16*)ws;                                   // 4096*1024*2  = 8,388,608
    u16*  Wo    = (u16*)(ws + 8388608);                       // 32000*1024*2 = 65,536,000
    float* wx    = (float*)(ws + 8388608 + 65536000);         // 4096*4
    float* biasc = wx + 4096;                                 // 4096*4
    u16*  h0    = (u16*)(biasc + 4096);                       // 32*1024*2
    float* c     = (float*)(h0 + 32 * 1024);                  // 32*1024*4
    u16*  A     = (u16*)(c + 32 * 1024);                      // 4096*1024*2
    unsigned* flags = (unsigned*)(A + (size_t)4096 * 1024);   // 64*4 B

    prep_w<<<16384, 256, 0, stream>>>(Wih, Whh, bih, bhh, Wcomb, wx, biasc, flags);
    prep_wout<<<32000, 256, 0, stream>>>(Wout, Wo);
    init_hc<<<512, 256, 0, stream>>>(enc, Wh, Wcp, h0, c);

    lstm_persist<<<NBLK_REC, 256, 0, stream>>>(Wcomb, wx, biasc, h0, c, y, A, flags);

    gemm_out<<<8000, 256, 0, stream>>>(A, Wo, bout, (float*)d_out);
}

// Round 5
// 1231.382 us; speedup vs baseline: 1.3682x; 1.0966x over previous
//
#include <hip/hip_runtime.h>
#include <hip/hip_bf16.h>
#include <stdint.h>

#define B_ 32
#define T_ 128
#define H_ 1024
#define V_ 32000
#define NBLK_REC 64

typedef unsigned short u16;
typedef __attribute__((ext_vector_type(8))) short short8;
typedef __attribute__((ext_vector_type(4))) float f32x4;

static __device__ __forceinline__ u16 f2bf(float f) {
    uint32_t u = __float_as_uint(f);
    uint32_t r = (u + 0x7FFFu + ((u >> 16) & 1u)) >> 16;
    return (u16)r;
}

static __device__ __forceinline__ float sigmf(float x) {
    return 1.0f / (1.0f + __expf(-x));
}

static __device__ __forceinline__ float tanh_f(float x) {
    x = fminf(fmaxf(x, -20.f), 20.f);
    float e = __expf(2.f * x);
    return (e - 1.f) / (e + 1.f);
}

// Direct global->LDS 16B copy (dest is wave-uniform base + lane*16 in HW).
static __device__ __forceinline__ void gload16(const void* g, void* l) {
    __builtin_amdgcn_global_load_lds(
        (const __attribute__((address_space(1))) uint32_t*)g,
        (__attribute__((address_space(3))) uint32_t*)(uint32_t)(uintptr_t)l,
        16, 0, 0);
}

// ---------------------------------------------------------------------------
// Prep: W_comb = W_ih[:,1:] + W_hh  (bf16), wx = W_ih[:,0], biasc = b_ih+b_hh
// Also zeroes the 64 producer flags (re-zeroed every launch/replay).
// ---------------------------------------------------------------------------
__global__ void prep_w(const float* __restrict__ Wih, const float* __restrict__ Whh,
                       const float* __restrict__ bih, const float* __restrict__ bhh,
                       u16* __restrict__ Wc, float* __restrict__ wx, float* __restrict__ biasc,
                       unsigned* __restrict__ flags) {
    int idx = blockIdx.x * 256 + threadIdx.x;      // 4096*1024 threads
    int r = idx >> 10, k = idx & 1023;
    float v = Wih[r * (H_ + 1) + 1 + k] + Whh[idx];
    Wc[idx] = f2bf(v);
    if (k == 0) {
        wx[r] = Wih[r * (H_ + 1)];
        biasc[r] = bih[r] + bhh[r];
    }
    if (idx < NBLK_REC) flags[idx] = 0u;
}

// W_out fp32 -> bf16
__global__ void prep_wout(const float* __restrict__ Wout, u16* __restrict__ Wo) {
    long long i = (long long)(blockIdx.x) * 256 + threadIdx.x;   // x4 elements each
    f32x4 v = *(const f32x4*)(Wout + i * 4);
    uint2 o;
    o.x = (uint32_t)f2bf(v[0]) | ((uint32_t)f2bf(v[1]) << 16);
    o.y = (uint32_t)f2bf(v[2]) | ((uint32_t)f2bf(v[3]) << 16);
    *(uint2*)(Wo + i * 4) = o;
}

// ---------------------------------------------------------------------------
// Init: h0 = enc @ W_h^T (bf16), c0 = enc @ W_c^T (fp32).
// One wave per (sel, j) row; W-row held in registers, reused for all 32 b.
// ---------------------------------------------------------------------------
__global__ void init_hc(const float* __restrict__ enc, const float* __restrict__ Wh,
                        const float* __restrict__ Wcp, u16* __restrict__ h0,
                        float* __restrict__ c0) {
    int gwid = blockIdx.x * 4 + (threadIdx.x >> 6);   // 2048 waves
    int lane = threadIdx.x & 63;
    int sel = gwid >> 10;                // 0: h, 1: c
    int j = gwid & 1023;
    const float* W = sel ? Wcp : Wh;
    const float* wrow = W + (size_t)j * H_;
    f32x4 wv[4];
#pragma unroll
    for (int it = 0; it < 4; ++it)
        wv[it] = *(const f32x4*)(wrow + it * 256 + lane * 4);
#pragma unroll 2
    for (int b = 0; b < B_; ++b) {
        const float* erow = enc + (size_t)b * H_;
        float acc = 0.f;
#pragma unroll
        for (int it = 0; it < 4; ++it) {
            f32x4 ev = *(const f32x4*)(erow + it * 256 + lane * 4);
            acc += wv[it][0] * ev[0] + wv[it][1] * ev[1] + wv[it][2] * ev[2] + wv[it][3] * ev[3];
        }
#pragma unroll
        for (int s = 32; s >= 1; s >>= 1) acc += __shfl_xor(acc, s, 64);
        if (lane == 0) {
            if (sel) c0[(size_t)b * H_ + j] = acc;
            else     h0[(size_t)b * H_ + j] = f2bf(acc);
        }
    }
}

// ---------------------------------------------------------------------------
// Persistent LSTM recurrence. 64 blocks x 256 threads; block owns j0=bid*16.
// Weights PINNED in registers (asm "+v": non-rematerializable) for all 128
// steps. h-state layout A[t][b][j] (t-major): producer stores are 8x 32B
// contiguous transactions per wave; consumer/gemm use uniform stride H_.
// Sync: producer stores h_t (agent scope), __syncthreads (drains vmcnt),
// tid0 relaxed-stores flags[bid]=t+1. Wave 0 polls flags[lane] w/ s_sleep.
// ---------------------------------------------------------------------------
__global__ __launch_bounds__(256, 1) void lstm_persist(
    const u16* __restrict__ Wc, const float* __restrict__ wx,
    const float* __restrict__ biasc, const u16* __restrict__ h0,
    const float* __restrict__ c0, const float* __restrict__ y,
    u16* __restrict__ A, unsigned* __restrict__ flags) {
    __shared__ float red[4][64 * 33];    // per-wave partial sums, padded (33)
    __shared__ float cs[16][33];         // cell state [jl][b], padded
    __shared__ float wxs[64], bcs[64];   // per-row x-weight / bias
    __shared__ float ys[32 * 129];       // y staged, padded stride 129

    int tid = threadIdx.x;
    int lane = tid & 63;
    int kw = tid >> 6;                   // wave id = K-slice
    int bid = blockIdx.x;
    int j0 = bid * 16;
    int jl = lane & 15;                  // A-row / B-col lane index
    int kc = (lane >> 4) * 8;            // k-offset within 32-chunk
    int jj = tid & 7, b = tid >> 3;      // pointwise mapping: j=2jj(+1), batch b

    // ---- one-time: weights to registers, pinned ----
    short8 afr[4][8];
    {
        const u16* abase = Wc + (size_t)(j0 + jl) * H_ + kw * 256 + kc;
#pragma unroll
        for (int g = 0; g < 4; ++g)
#pragma unroll
            for (int ks = 0; ks < 8; ++ks)
                afr[g][ks] = *(const short8*)(abase + (size_t)g * H_ * H_ + ks * 32);
    }
#pragma unroll
    for (int g = 0; g < 4; ++g)
#pragma unroll
        for (int ks = 0; ks < 8; ++ks)
            asm volatile("" : "+v"(afr[g][ks]));   // pin: defeat remat/reload

    // ---- one-time: stage wx/bias/c0/y into LDS ----
    if (tid < 64) {
        int g = tid >> 4, q = tid & 15;
        wxs[tid] = wx[(size_t)g * H_ + j0 + q];
        bcs[tid] = biasc[(size_t)g * H_ + j0 + q];
    }
#pragma unroll
    for (int i = tid; i < B_ * T_; i += 256)
        ys[(i >> 7) * 129 + (i & 127)] = y[i];
    cs[2 * jj][b]     = c0[(size_t)b * H_ + j0 + 2 * jj];
    cs[2 * jj + 1][b] = c0[(size_t)b * H_ + j0 + 2 * jj + 1];
    __syncthreads();

    for (int t = 0; t < T_; ++t) {
        const u16* hp = (t == 0) ? h0 : (A + (size_t)(t - 1) * B_ * H_);

        // ---- wait for all producers of h_{t-1}: wave 0 polls, rest park ----
        if (t > 0) {
            if (kw == 0) {
                unsigned target = (unsigned)t;
                const unsigned* fp = &flags[lane];
                int guard = 0;
                for (;;) {
                    unsigned v = __hip_atomic_load(fp, __ATOMIC_RELAXED, __HIP_MEMORY_SCOPE_AGENT);
                    if (__all(v >= target)) break;
                    __builtin_amdgcn_s_sleep(1);
                    if (++guard > 10000000) break;   // safety; never triggers co-resident
                }
                __atomic_signal_fence(__ATOMIC_ACQUIRE);
            }
            __syncthreads();
        }

        // ---- load B-frags (h_prev, layout [b][j] stride H_) and MFMA ----
        short8 bfr0[8], bfr1[8];
        {
            const u16* hb = hp + (size_t)jl * H_ + kw * 256 + kc;
#pragma unroll
            for (int ks = 0; ks < 8; ++ks) {
                bfr0[ks] = *(const short8*)(hb + ks * 32);
                bfr1[ks] = *(const short8*)(hb + (size_t)16 * H_ + ks * 32);
            }
        }
        f32x4 acc[4][2] = {};
#pragma unroll
        for (int ks = 0; ks < 8; ++ks) {
#pragma unroll
            for (int g = 0; g < 4; ++g) {
                acc[g][0] = __builtin_amdgcn_mfma_f32_16x16x32_bf16(afr[g][ks], bfr0[ks], acc[g][0], 0, 0, 0);
                acc[g][1] = __builtin_amdgcn_mfma_f32_16x16x32_bf16(afr[g][ks], bfr1[ks], acc[g][1], 0, 0, 0);
            }
        }
        // ---- partials to LDS ----
        int r0 = (lane >> 4) * 4;
#pragma unroll
        for (int g = 0; g < 4; ++g)
#pragma unroll
            for (int bt = 0; bt < 2; ++bt)
#pragma unroll
                for (int r = 0; r < 4; ++r)
                    red[kw][(g * 16 + r0 + r) * 33 + bt * 16 + jl] = acc[g][bt][r];
        __syncthreads();

        // ---- pointwise cell update; write h_t (agent-scope) ----
        {
            float yv = ys[b * 129 + t];
            float hv[2];
#pragma unroll
            for (int s = 0; s < 2; ++s) {
                int jlx = 2 * jj + s;
                float pre[4];
#pragma unroll
                for (int g = 0; g < 4; ++g) {
                    int row = (g * 16 + jlx) * 33 + b;
                    pre[g] = red[0][row] + red[1][row] + red[2][row] + red[3][row]
                           + wxs[g * 16 + jlx] * yv + bcs[g * 16 + jlx];
                }
                float iv = sigmf(pre[0]);
                float fv = sigmf(pre[1]);
                float gv = tanh_f(pre[2]);
                float ov = sigmf(pre[3]);
                float cv = fv * cs[jlx][b] + iv * gv;
                cs[jlx][b] = cv;
                hv[s] = ov * tanh_f(cv);
            }
            uint32_t pk = (uint32_t)f2bf(hv[0]) | ((uint32_t)f2bf(hv[1]) << 16);
            // A[t][b][j]: lanes jj=0..7 contiguous 32B, 8 lines per wave.
            __hip_atomic_store((uint32_t*)(A + ((size_t)t * B_ + b) * H_ + j0 + 2 * jj),
                               pk, __ATOMIC_RELAXED, __HIP_MEMORY_SCOPE_AGENT);
        }
        // Drains every thread's vmcnt -> all h_t stores at the coherence
        // point; also protects red[]/cs[] for next iter.
        __syncthreads();
        if (tid == 0)
            __hip_atomic_store(&flags[bid], (unsigned)(t + 1),
                               __ATOMIC_RELAXED, __HIP_MEMORY_SCOPE_AGENT);
    }
}

// ---------------------------------------------------------------------------
// Output GEMM: C[row][n] = sum_k A[t][b][k] * Wo[n][k] + b_out[n]
// A layout is [t][b][j] (t-major). m-tile = batch mb; tile rows = t 0..127.
// 128x128 tile, BK=32, global_load_lds width-16 linear staging, XCD-bijective
// swizzle. Epilogue transposes C through LDS -> contiguous 512B t-rows.
// ---------------------------------------------------------------------------
#define TRS 132   // transpose-buffer row stride in words (528B): <=2-way banks
__global__ __launch_bounds__(256) void gemm_out(
    const u16* __restrict__ A, const u16* __restrict__ Wo,
    const float* __restrict__ bout, float* __restrict__ out) {
    __shared__ __align__(16) uint8_t smem[32 * TRS * 4];   // 16896B; aliases staging
    u16* As = (u16*)smem;               // 128*32 u16 = 8KB
    u16* Bs = As + 128 * 32;            // 8KB
    float* tr = (float*)smem;           // epilogue transpose buffer

    int orig = blockIdx.x;                       // 8000 = 8 XCDs * 1000
    int w = (orig & 7) * 1000 + (orig >> 3);     // bijective XCD chunking
    int mb = w & 31;                             // m-block == batch b
    int nb = w >> 5;                             // 250 n-blocks
    int n0 = nb * 128;

    int tid = threadIdx.x, lane = tid & 63, wid = tid >> 6;
    int wm = wid >> 1, wn = wid & 1;

    f32x4 acc[4][4] = {};

    int srow = tid >> 2;            // 0..63 (= t index)
    int scol = (tid & 3) * 8;       // k-offset within 32-chunk
    const u16* Ag = A + ((size_t)srow * B_ + mb) * H_ + scol;    // A[t][mb][k]
    const u16* Bg = Wo + (size_t)(n0 + srow) * H_ + scol;
    u16* AsD0 = &As[tid * 8];            // linear: byte off = tid*16
    u16* AsD1 = &As[64 * 32 + tid * 8];
    u16* BsD0 = &Bs[tid * 8];
    u16* BsD1 = &Bs[64 * 32 + tid * 8];

    int kc = (lane >> 4) * 8;
    int frow = lane & 15;

    for (int ks = 0; ks < 32; ++ks) {
        int k0 = ks * 32;
        __syncthreads();   // previous iter's frag reads done before overwrite
        gload16(Ag + k0, AsD0);
        gload16(Ag + (size_t)64 * B_ * H_ + k0, AsD1);   // t = srow+64
        gload16(Bg + k0, BsD0);
        gload16(Bg + (size_t)64 * H_ + k0, BsD1);
        __syncthreads();   // vmcnt(0) drain: staged tile visible

        short8 af[4], bf[4];
#pragma unroll
        for (int mt = 0; mt < 4; ++mt)
            af[mt] = *(const short8*)(&As[(wm * 64 + mt * 16 + frow) * 32 + kc]);
#pragma unroll
        for (int nt = 0; nt < 4; ++nt)
            bf[nt] = *(const short8*)(&Bs[(wn * 64 + nt * 16 + frow) * 32 + kc]);
#pragma unroll
        for (int mt = 0; mt < 4; ++mt)
#pragma unroll
            for (int nt = 0; nt < 4; ++nt)
                acc[mt][nt] = __builtin_amdgcn_mfma_f32_16x16x32_bf16(af[mt], bf[nt], acc[mt][nt], 0, 0, 0);
    }

    // ---- epilogue: bias + transpose through LDS, coalesced t-major stores --
    float biasv[4];
#pragma unroll
    for (int nt = 0; nt < 4; ++nt)
        biasv[nt] = bout[n0 + wn * 64 + nt * 16 + (lane & 15)];

    int b = mb;
#pragma unroll
    for (int p = 0; p < 4; ++p) {
        __syncthreads();   // K-loop frag reads / previous pass reads done
        if (wn == (p >> 1)) {
#pragma unroll
            for (int hh = 0; hh < 2; ++hh) {
                int nt = (p & 1) * 2 + hh;
                int nl = ((nt & 1) << 4) + (lane & 15);   // row within 32-group
#pragma unroll
                for (int mt = 0; mt < 4; ++mt) {
                    f32x4 v = acc[mt][nt];
                    float bs = biasv[nt];
                    v[0] += bs; v[1] += bs; v[2] += bs; v[3] += bs;
                    int t = wm * 64 + mt * 16 + ((lane >> 4) << 2);
                    *(f32x4*)&tr[nl * TRS + t] = v;
                }
            }
        }
        __syncthreads();
        {
            int row = tid >> 3;              // 0..31
            int c0 = (tid & 7) * 16;         // float offset within t-row
            int n = n0 + p * 32 + row;
            float* dst = out + ((size_t)b * V_ + n) * T_ + c0;
            const float* srcp = &tr[row * TRS + c0];
            f32x4 v0 = *(const f32x4*)(srcp);
            f32x4 v1 = *(const f32x4*)(srcp + 4);
            f32x4 v2 = *(const f32x4*)(srcp + 8);
            f32x4 v3 = *(const f32x4*)(srcp + 12);
            *(f32x4*)(dst)      = v0;
            *(f32x4*)(dst + 4)  = v1;
            *(f32x4*)(dst + 8)  = v2;
            *(f32x4*)(dst + 12) = v3;
        }
    }
}

// ---------------------------------------------------------------------------
extern "C" void kernel_launch(void* const* d_in, const int* in_sizes, int n_in,
                              void* d_out, int out_size, void* d_ws, size_t ws_size,
                              hipStream_t stream) {
    const float* y    = (const float*)d_in[0];   // [B,T]
    const float* enc  = (const float*)d_in[1];   // [B,H]
    const float* Wh   = (const float*)d_in[2];   // [H,H]
    const float* Wcp  = (const float*)d_in[3];   // [H,H]
    const float* Wih  = (const float*)d_in[4];   // [4H,1+H]
    const float* Whh  = (const float*)d_in[5];   // [4H,H]
    const float* bih  = (const float*)d_in[6];   // [4H]
    const float* bhh  = (const float*)d_in[7];   // [4H]
    const float* Wout = (const float*)d_in[8];   // [V,H]
    const float* bout = (const float*)d_in[9];   // [V]

    uint8_t* ws = (uint8_t*)d_ws;
    u16*  Wcomb = (u16*)ws;                                   // 4096*1024*2  = 8,388,608
    u16*  Wo    = (u16*)(ws + 8388608);                       // 32000*1024*2 = 65,536,000
    float* wx    = (float*)(ws + 8388608 + 65536000);         // 4096*4
    float* biasc = wx + 4096;                                 // 4096*4
    u16*  h0    = (u16*)(biasc + 4096);                       // 32*1024*2
    float* c     = (float*)(h0 + 32 * 1024);                  // 32*1024*4
    u16*  A     = (u16*)(c + 32 * 1024);                      // [T][B][H] bf16
    unsigned* flags = (unsigned*)(A + (size_t)4096 * 1024);   // 64*4 B

    prep_w<<<16384, 256, 0, stream>>>(Wih, Whh, bih, bhh, Wcomb, wx, biasc, flags);
    prep_wout<<<32000, 256, 0, stream>>>(Wout, Wo);
    init_hc<<<512, 256, 0, stream>>>(enc, Wh, Wcp, h0, c);

    lstm_persist<<<NBLK_REC, 256, 0, stream>>>(Wcomb, wx, biasc, h0, c, y, A, flags);

    gemm_out<<<8000, 256, 0, stream>>>(A, Wo, bout, (float*)d_out);
}

// Round 6
// 1179.067 us; speedup vs baseline: 1.4289x; 1.0444x over previous
//
#include <hip/hip_runtime.h>
#include <hip/hip_bf16.h>
#include <stdint.h>

#define B_ 32
#define T_ 128
#define H_ 1024
#define V_ 32000
#define NBLK_REC 64

typedef unsigned short u16;
typedef __attribute__((ext_vector_type(8))) short short8;
typedef __attribute__((ext_vector_type(4))) float f32x4;

static __device__ __forceinline__ u16 f2bf(float f) {
    uint32_t u = __float_as_uint(f);
    uint32_t r = (u + 0x7FFFu + ((u >> 16) & 1u)) >> 16;
    return (u16)r;
}

static __device__ __forceinline__ float sigmf(float x) {
    return 1.0f / (1.0f + __expf(-x));
}

static __device__ __forceinline__ float tanh_f(float x) {
    x = fminf(fmaxf(x, -20.f), 20.f);
    float e = __expf(2.f * x);
    return (e - 1.f) / (e + 1.f);
}

// Direct global->LDS 16B copy (dest is wave-uniform base + lane*16 in HW).
static __device__ __forceinline__ void gload16(const void* g, void* l) {
    __builtin_amdgcn_global_load_lds(
        (const __attribute__((address_space(1))) uint32_t*)g,
        (__attribute__((address_space(3))) uint32_t*)(uint32_t)(uintptr_t)l,
        16, 0, 0);
}

// ---------------------------------------------------------------------------
// Prep: W_comb = W_ih[:,1:] + W_hh  (bf16), wx = W_ih[:,0], biasc = b_ih+b_hh
// Also zeroes the 64 producer flags (re-zeroed every launch/replay).
// ---------------------------------------------------------------------------
__global__ void prep_w(const float* __restrict__ Wih, const float* __restrict__ Whh,
                       const float* __restrict__ bih, const float* __restrict__ bhh,
                       u16* __restrict__ Wc, float* __restrict__ wx, float* __restrict__ biasc,
                       unsigned* __restrict__ flags) {
    int idx = blockIdx.x * 256 + threadIdx.x;      // 4096*1024 threads
    int r = idx >> 10, k = idx & 1023;
    float v = Wih[r * (H_ + 1) + 1 + k] + Whh[idx];
    Wc[idx] = f2bf(v);
    if (k == 0) {
        wx[r] = Wih[r * (H_ + 1)];
        biasc[r] = bih[r] + bhh[r];
    }
    if (idx < NBLK_REC) flags[idx] = 0u;
}

// W_out fp32 -> bf16
__global__ void prep_wout(const float* __restrict__ Wout, u16* __restrict__ Wo) {
    long long i = (long long)(blockIdx.x) * 256 + threadIdx.x;   // x4 elements each
    f32x4 v = *(const f32x4*)(Wout + i * 4);
    uint2 o;
    o.x = (uint32_t)f2bf(v[0]) | ((uint32_t)f2bf(v[1]) << 16);
    o.y = (uint32_t)f2bf(v[2]) | ((uint32_t)f2bf(v[3]) << 16);
    *(uint2*)(Wo + i * 4) = o;
}

// ---------------------------------------------------------------------------
// Init: h0 = enc @ W_h^T (bf16), c0 = enc @ W_c^T (fp32).
// One wave per (sel, j) row; W-row held in registers, reused for all 32 b.
// ---------------------------------------------------------------------------
__global__ void init_hc(const float* __restrict__ enc, const float* __restrict__ Wh,
                        const float* __restrict__ Wcp, u16* __restrict__ h0,
                        float* __restrict__ c0) {
    int gwid = blockIdx.x * 4 + (threadIdx.x >> 6);   // 2048 waves
    int lane = threadIdx.x & 63;
    int sel = gwid >> 10;                // 0: h, 1: c
    int j = gwid & 1023;
    const float* W = sel ? Wcp : Wh;
    const float* wrow = W + (size_t)j * H_;
    f32x4 wv[4];
#pragma unroll
    for (int it = 0; it < 4; ++it)
        wv[it] = *(const f32x4*)(wrow + it * 256 + lane * 4);
#pragma unroll 2
    for (int b = 0; b < B_; ++b) {
        const float* erow = enc + (size_t)b * H_;
        float acc = 0.f;
#pragma unroll
        for (int it = 0; it < 4; ++it) {
            f32x4 ev = *(const f32x4*)(erow + it * 256 + lane * 4);
            acc += wv[it][0] * ev[0] + wv[it][1] * ev[1] + wv[it][2] * ev[2] + wv[it][3] * ev[3];
        }
#pragma unroll
        for (int s = 32; s >= 1; s >>= 1) acc += __shfl_xor(acc, s, 64);
        if (lane == 0) {
            if (sel) c0[(size_t)b * H_ + j] = acc;
            else     h0[(size_t)b * H_ + j] = f2bf(acc);
        }
    }
}

// ---------------------------------------------------------------------------
// Persistent LSTM recurrence. 64 blocks x 512 threads (8 K-waves of 128 k).
// Block owns j0=bid*16 (64 gate rows). Per-thread weights afr[4][4] = 64 VGPR
// -> cheap register residency. Wave w polls ONLY its slice's 8 producer flags
// (blocks 8w..8w+7) and starts its h loads immediately; 8 partial sums are
// K-reduced in LDS. h layout A[t][b][j] (t-major). Sync: producer h stores
// (agent scope), __syncthreads drains vmcnt, tid0 relaxed flag store.
// ---------------------------------------------------------------------------
__global__ __launch_bounds__(512, 1) void lstm_persist(
    const u16* __restrict__ Wc, const float* __restrict__ wx,
    const float* __restrict__ biasc, const u16* __restrict__ h0,
    const float* __restrict__ c0, const float* __restrict__ y,
    u16* __restrict__ A, unsigned* __restrict__ flags) {
    __shared__ float red[8][64 * 33];    // 8 K-wave partials, padded (67.6KB)
    __shared__ float cs[16][33];         // cell state [jl][b], padded
    __shared__ float wxs[64], bcs[64];   // per-row x-weight / bias
    __shared__ float ys[32 * 129];       // y staged, padded stride 129

    int tid = threadIdx.x;
    int lane = tid & 63;
    int w = tid >> 6;                    // K-wave id 0..7 (k-slice w*128)
    int bid = blockIdx.x;
    int j0 = bid * 16;
    int jl = lane & 15;                  // A-row / B-col lane index
    int kc = (lane >> 4) * 8;            // k-offset within 32-chunk
    int jj = tid & 7, b = tid >> 3;      // pointwise mapping (tid<256)

    // ---- one-time: weights to registers (64 VGPRs), pinned ----
    short8 afr[4][4];
    {
        const u16* abase = Wc + (size_t)(j0 + jl) * H_ + w * 128 + kc;
#pragma unroll
        for (int g = 0; g < 4; ++g)
#pragma unroll
            for (int ks = 0; ks < 4; ++ks)
                afr[g][ks] = *(const short8*)(abase + (size_t)g * H_ * H_ + ks * 32);
    }
#pragma unroll
    for (int g = 0; g < 4; ++g)
#pragma unroll
        for (int ks = 0; ks < 4; ++ks)
            asm volatile("" : "+v"(afr[g][ks]));   // pin: defeat remat/reload

    // ---- one-time: stage wx/bias/y/c0 into LDS ----
    if (tid < 64) {
        int g = tid >> 4, q = tid & 15;
        wxs[tid] = wx[(size_t)g * H_ + j0 + q];
        bcs[tid] = biasc[(size_t)g * H_ + j0 + q];
    }
#pragma unroll
    for (int i = tid; i < B_ * T_; i += 512)
        ys[(i >> 7) * 129 + (i & 127)] = y[i];
    if (tid < 256) {
        cs[2 * jj][b]     = c0[(size_t)b * H_ + j0 + 2 * jj];
        cs[2 * jj + 1][b] = c0[(size_t)b * H_ + j0 + 2 * jj + 1];
    }
    __syncthreads();

    for (int t = 0; t < T_; ++t) {
        const u16* hp = (t == 0) ? h0 : (A + (size_t)(t - 1) * B_ * H_);

        // ---- per-wave slice wait: only the 8 producers of k-slice w ----
        if (t > 0) {
            const unsigned* fp = &flags[w * 8 + (lane & 7)];
            unsigned target = (unsigned)t;
            int guard = 0;
            for (;;) {
                unsigned v = __hip_atomic_load(fp, __ATOMIC_RELAXED, __HIP_MEMORY_SCOPE_AGENT);
                if (__all(v >= target)) break;
                if (++guard > 20000000) break;   // hang-safety; never triggers co-resident
            }
            __atomic_signal_fence(__ATOMIC_ACQUIRE);
        }

        // ---- load h b-frags for this wave's k-slice and MFMA ----
        short8 bfr0[4], bfr1[4];
        {
            const u16* hb = hp + (size_t)jl * H_ + w * 128 + kc;
#pragma unroll
            for (int ks = 0; ks < 4; ++ks) {
                bfr0[ks] = *(const short8*)(hb + ks * 32);
                bfr1[ks] = *(const short8*)(hb + (size_t)16 * H_ + ks * 32);
            }
        }
        f32x4 acc[4][2] = {};
#pragma unroll
        for (int ks = 0; ks < 4; ++ks) {
#pragma unroll
            for (int g = 0; g < 4; ++g) {
                acc[g][0] = __builtin_amdgcn_mfma_f32_16x16x32_bf16(afr[g][ks], bfr0[ks], acc[g][0], 0, 0, 0);
                acc[g][1] = __builtin_amdgcn_mfma_f32_16x16x32_bf16(afr[g][ks], bfr1[ks], acc[g][1], 0, 0, 0);
            }
        }
        // ---- partials to LDS ----
        int r0 = (lane >> 4) * 4;
#pragma unroll
        for (int g = 0; g < 4; ++g)
#pragma unroll
            for (int bt = 0; bt < 2; ++bt)
#pragma unroll
                for (int r = 0; r < 4; ++r)
                    red[w][(g * 16 + r0 + r) * 33 + bt * 16 + jl] = acc[g][bt][r];
        __syncthreads();

        // ---- pointwise cell update (tid<256); write h_t (agent-scope) ----
        if (tid < 256) {
            float yv = ys[b * 129 + t];
            float hv[2];
#pragma unroll
            for (int s = 0; s < 2; ++s) {
                int jlx = 2 * jj + s;
                float pre = wxs[0 * 16 + jlx] * yv;   // placeholder replaced below
                (void)pre;
                float pg[4];
#pragma unroll
                for (int g = 0; g < 4; ++g) {
                    int row = (g * 16 + jlx) * 33 + b;
                    float sum = red[0][row];
#pragma unroll
                    for (int ww = 1; ww < 8; ++ww) sum += red[ww][row];
                    pg[g] = sum + wxs[g * 16 + jlx] * yv + bcs[g * 16 + jlx];
                }
                float iv = sigmf(pg[0]);
                float fv = sigmf(pg[1]);
                float gv = tanh_f(pg[2]);
                float ov = sigmf(pg[3]);
                float cv = fv * cs[jlx][b] + iv * gv;
                cs[jlx][b] = cv;
                hv[s] = ov * tanh_f(cv);
            }
            uint32_t pk = (uint32_t)f2bf(hv[0]) | ((uint32_t)f2bf(hv[1]) << 16);
            // A[t][b][j]: lanes jj=0..7 contiguous 32B per batch.
            __hip_atomic_store((uint32_t*)(A + ((size_t)t * B_ + b) * H_ + j0 + 2 * jj),
                               pk, __ATOMIC_RELAXED, __HIP_MEMORY_SCOPE_AGENT);
        }
        // Drains every thread's vmcnt -> h_t stores at the coherence point;
        // also protects red[]/cs[] for the next iteration.
        __syncthreads();
        if (tid == 0)
            __hip_atomic_store(&flags[bid], (unsigned)(t + 1),
                               __ATOMIC_RELAXED, __HIP_MEMORY_SCOPE_AGENT);
    }
}

// ---------------------------------------------------------------------------
// Output GEMM: C[row][n] = sum_k A[t][b][k] * Wo[n][k] + b_out[n]
// A layout is [t][b][j] (t-major). m-tile = batch mb; tile rows = t 0..127.
// 128x128 tile, BK=32, global_load_lds width-16 linear staging, XCD-bijective
// swizzle. Epilogue transposes C through LDS -> contiguous 512B t-rows.
// ---------------------------------------------------------------------------
#define TRS 132   // transpose-buffer row stride in words (528B): <=2-way banks
__global__ __launch_bounds__(256) void gemm_out(
    const u16* __restrict__ A, const u16* __restrict__ Wo,
    const float* __restrict__ bout, float* __restrict__ out) {
    __shared__ __align__(16) uint8_t smem[32 * TRS * 4];   // 16896B; aliases staging
    u16* As = (u16*)smem;               // 128*32 u16 = 8KB
    u16* Bs = As + 128 * 32;            // 8KB
    float* tr = (float*)smem;           // epilogue transpose buffer

    int orig = blockIdx.x;                       // 8000 = 8 XCDs * 1000
    int w = (orig & 7) * 1000 + (orig >> 3);     // bijective XCD chunking
    int mb = w & 31;                             // m-block == batch b
    int nb = w >> 5;                             // 250 n-blocks
    int n0 = nb * 128;

    int tid = threadIdx.x, lane = tid & 63, wid = tid >> 6;
    int wm = wid >> 1, wn = wid & 1;

    f32x4 acc[4][4] = {};

    int srow = tid >> 2;            // 0..63 (= t index)
    int scol = (tid & 3) * 8;       // k-offset within 32-chunk
    const u16* Ag = A + ((size_t)srow * B_ + mb) * H_ + scol;    // A[t][mb][k]
    const u16* Bg = Wo + (size_t)(n0 + srow) * H_ + scol;
    u16* AsD0 = &As[tid * 8];            // linear: byte off = tid*16
    u16* AsD1 = &As[64 * 32 + tid * 8];
    u16* BsD0 = &Bs[tid * 8];
    u16* BsD1 = &Bs[64 * 32 + tid * 8];

    int kc = (lane >> 4) * 8;
    int frow = lane & 15;

    for (int ks = 0; ks < 32; ++ks) {
        int k0 = ks * 32;
        __syncthreads();   // previous iter's frag reads done before overwrite
        gload16(Ag + k0, AsD0);
        gload16(Ag + (size_t)64 * B_ * H_ + k0, AsD1);   // t = srow+64
        gload16(Bg + k0, BsD0);
        gload16(Bg + (size_t)64 * H_ + k0, BsD1);
        __syncthreads();   // vmcnt(0) drain: staged tile visible

        short8 af[4], bf[4];
#pragma unroll
        for (int mt = 0; mt < 4; ++mt)
            af[mt] = *(const short8*)(&As[(wm * 64 + mt * 16 + frow) * 32 + kc]);
#pragma unroll
        for (int nt = 0; nt < 4; ++nt)
            bf[nt] = *(const short8*)(&Bs[(wn * 64 + nt * 16 + frow) * 32 + kc]);
#pragma unroll
        for (int mt = 0; mt < 4; ++mt)
#pragma unroll
            for (int nt = 0; nt < 4; ++nt)
                acc[mt][nt] = __builtin_amdgcn_mfma_f32_16x16x32_bf16(af[mt], bf[nt], acc[mt][nt], 0, 0, 0);
    }

    // ---- epilogue: bias + transpose through LDS, coalesced t-major stores --
    float biasv[4];
#pragma unroll
    for (int nt = 0; nt < 4; ++nt)
        biasv[nt] = bout[n0 + wn * 64 + nt * 16 + (lane & 15)];

    int b = mb;
#pragma unroll
    for (int p = 0; p < 4; ++p) {
        __syncthreads();   // K-loop frag reads / previous pass reads done
        if (wn == (p >> 1)) {
#pragma unroll
            for (int hh = 0; hh < 2; ++hh) {
                int nt = (p & 1) * 2 + hh;
                int nl = ((nt & 1) << 4) + (lane & 15);   // row within 32-group
#pragma unroll
                for (int mt = 0; mt < 4; ++mt) {
                    f32x4 v = acc[mt][nt];
                    float bs = biasv[nt];
                    v[0] += bs; v[1] += bs; v[2] += bs; v[3] += bs;
                    int t = wm * 64 + mt * 16 + ((lane >> 4) << 2);
                    *(f32x4*)&tr[nl * TRS + t] = v;
                }
            }
        }
        __syncthreads();
        {
            int row = tid >> 3;              // 0..31
            int c0 = (tid & 7) * 16;         // float offset within t-row
            int n = n0 + p * 32 + row;
            float* dst = out + ((size_t)b * V_ + n) * T_ + c0;
            const float* srcp = &tr[row * TRS + c0];
            f32x4 v0 = *(const f32x4*)(srcp);
            f32x4 v1 = *(const f32x4*)(srcp + 4);
            f32x4 v2 = *(const f32x4*)(srcp + 8);
            f32x4 v3 = *(const f32x4*)(srcp + 12);
            *(f32x4*)(dst)      = v0;
            *(f32x4*)(dst + 4)  = v1;
            *(f32x4*)(dst + 8)  = v2;
            *(f32x4*)(dst + 12) = v3;
        }
    }
}

// ---------------------------------------------------------------------------
extern "C" void kernel_launch(void* const* d_in, const int* in_sizes, int n_in,
                              void* d_out, int out_size, void* d_ws, size_t ws_size,
                              hipStream_t stream) {
    const float* y    = (const float*)d_in[0];   // [B,T]
    const float* enc  = (const float*)d_in[1];   // [B,H]
    const float* Wh   = (const float*)d_in[2];   // [H,H]
    const float* Wcp  = (const float*)d_in[3];   // [H,H]
    const float* Wih  = (const float*)d_in[4];   // [4H,1+H]
    const float* Whh  = (const float*)d_in[5];   // [4H,H]
    const float* bih  = (const float*)d_in[6];   // [4H]
    const float* bhh  = (const float*)d_in[7];   // [4H]
    const float* Wout = (const float*)d_in[8];   // [V,H]
    const float* bout = (const float*)d_in[9];   // [V]

    uint8_t* ws = (uint8_t*)d_ws;
    u16*  Wcomb = (u16*)ws;                                   // 4096*1024*2  = 8,388,608
    u16*  Wo    = (u16*)(ws + 8388608);                       // 32000*1024*2 = 65,536,000
    float* wx    = (float*)(ws + 8388608 + 65536000);         // 4096*4
    float* biasc = wx + 4096;                                 // 4096*4
    u16*  h0    = (u16*)(biasc + 4096);                       // 32*1024*2
    float* c     = (float*)(h0 + 32 * 1024);                  // 32*1024*4
    u16*  A     = (u16*)(c + 32 * 1024);                      // [T][B][H] bf16
    unsigned* flags = (unsigned*)(A + (size_t)4096 * 1024);   // 64*4 B

    prep_w<<<16384, 256, 0, stream>>>(Wih, Whh, bih, bhh, Wcomb, wx, biasc, flags);
    prep_wout<<<32000, 256, 0, stream>>>(Wout, Wo);
    init_hc<<<512, 256, 0, stream>>>(enc, Wh, Wcp, h0, c);

    lstm_persist<<<NBLK_REC, 512, 0, stream>>>(Wcomb, wx, biasc, h0, c, y, A, flags);

    gemm_out<<<8000, 256, 0, stream>>>(A, Wo, bout, (float*)d_out);
}